// Round 2
// baseline (86.630 us; speedup 1.0000x reference)
//
#include <hip/hip_runtime.h>
#include <math.h>

#define BB 512
#define SS 200
#define DD 64
#define VV 100000
#define NZB 1536
#define GRID (BB + NZB)

__device__ __forceinline__ float lane_bcast(float v, int l) {
    return __uint_as_float(__builtin_amdgcn_readlane(__float_as_uint(v), l));
}

__device__ __forceinline__ float gauss_pdf(float xx, float mu, float sg) {
    float z = (xx - mu) / sg;
    return expf(-0.5f * z * z - logf(sg) - 0.9189385332046727f);
}

__global__ __launch_bounds__(256) void k1_zero_and_compute(
    const float* __restrict__ x, const int* __restrict__ x_ids,
    const float* __restrict__ tg, const int* __restrict__ cla,
    const float* __restrict__ Wq, const float* __restrict__ bq,
    const float* __restrict__ Wk, const float* __restrict__ bk,
    const float* __restrict__ wv, const float* __restrict__ bv,
    const float* __restrict__ theta, float* __restrict__ out,
    int2* __restrict__ wslist)
{
    const int blk = blockIdx.x;
    const int tid = threadIdx.x;

    if (blk >= BB) {
        // ---- zeroing role: stream 204.8 MB of zeros, write-bound ----
        float4* __restrict__ o4 = (float4*)out;
        const float4 z4 = make_float4(0.f, 0.f, 0.f, 0.f);
        const size_t total4 = (size_t)BB * VV / 4;           // 12.8M
        for (size_t i = (size_t)(blk - BB) * 256 + tid; i < total4;
             i += (size_t)NZB * 256)
            o4[i] = z4;
        return;
    }

    // ---- compute role: row b -> compact (id, val) list in ws ----
    const int b    = blk;
    const int lane = tid & 63;
    const int wave = tid >> 6;

    __shared__ float sTh[17];
    __shared__ float sx0[DD];
    __shared__ float sKp[4][DD];
    __shared__ float sScore[SS];
    __shared__ float sRed[8];

    if (tid < 17) sTh[tid] = theta[tid];
    if (tid < DD) sx0[tid] = x[(size_t)b * SS * DD + tid];
    __syncthreads();

    // k_b partials: wave w covers j in [w*16, w*16+16); lane = output dim d
    {
        float acc = 0.f;
        #pragma unroll
        for (int jj = 0; jj < 16; ++jj) {
            int j = wave * 16 + jj;
            acc = fmaf(sx0[j], Wk[j * DD + lane], acc);
        }
        sKp[wave][lane] = acc;
    }

    // Wq column for d = lane, in 16 NAMED float4 regs (no indexable array ->
    // no scratch; round-1 profile showed VGPR=48 i.e. the array version spilled)
    const float* __restrict__ wp = Wq + lane;
#define LW(q) const float4 w##q = make_float4(wp[(4*q+0)*DD], wp[(4*q+1)*DD], \
                                              wp[(4*q+2)*DD], wp[(4*q+3)*DD]);
    LW(0) LW(1) LW(2) LW(3) LW(4) LW(5) LW(6) LW(7)
    LW(8) LW(9) LW(10) LW(11) LW(12) LW(13) LW(14) LW(15)
#undef LW
    const float wvl = wv[lane];
    const float bvv = bv[0];

    __syncthreads();

    const float kpl = sKp[0][lane] + sKp[1][lane] + sKp[2][lane] + sKp[3][lane]
                    + bk[lane] + bq[lane];

    // scores: one wave per sequence position s; lane = feature dim d
    const float* __restrict__ xb = x + (size_t)b * SS * DD;
    for (int s = wave; s < SS; s += 4) {
        float xs = xb[s * DD + lane];       // lane j holds x[b,s,j]
        float a0 = 0.f, a1 = 0.f, a2 = 0.f, a3 = 0.f;  // 4-way ILP
#define ST(J, C, A) A = fmaf(lane_bcast(xs, J), C, A);
        ST(0,w0.x,a0)  ST(1,w0.y,a1)  ST(2,w0.z,a2)  ST(3,w0.w,a3)
        ST(4,w1.x,a0)  ST(5,w1.y,a1)  ST(6,w1.z,a2)  ST(7,w1.w,a3)
        ST(8,w2.x,a0)  ST(9,w2.y,a1)  ST(10,w2.z,a2) ST(11,w2.w,a3)
        ST(12,w3.x,a0) ST(13,w3.y,a1) ST(14,w3.z,a2) ST(15,w3.w,a3)
        ST(16,w4.x,a0) ST(17,w4.y,a1) ST(18,w4.z,a2) ST(19,w4.w,a3)
        ST(20,w5.x,a0) ST(21,w5.y,a1) ST(22,w5.z,a2) ST(23,w5.w,a3)
        ST(24,w6.x,a0) ST(25,w6.y,a1) ST(26,w6.z,a2) ST(27,w6.w,a3)
        ST(28,w7.x,a0) ST(29,w7.y,a1) ST(30,w7.z,a2) ST(31,w7.w,a3)
        ST(32,w8.x,a0) ST(33,w8.y,a1) ST(34,w8.z,a2) ST(35,w8.w,a3)
        ST(36,w9.x,a0) ST(37,w9.y,a1) ST(38,w9.z,a2) ST(39,w9.w,a3)
        ST(40,w10.x,a0) ST(41,w10.y,a1) ST(42,w10.z,a2) ST(43,w10.w,a3)
        ST(44,w11.x,a0) ST(45,w11.y,a1) ST(46,w11.z,a2) ST(47,w11.w,a3)
        ST(48,w12.x,a0) ST(49,w12.y,a1) ST(50,w12.z,a2) ST(51,w12.w,a3)
        ST(52,w13.x,a0) ST(53,w13.y,a1) ST(54,w13.z,a2) ST(55,w13.w,a3)
        ST(56,w14.x,a0) ST(57,w14.y,a1) ST(58,w14.z,a2) ST(59,w14.w,a3)
        ST(60,w15.x,a0) ST(61,w15.y,a1) ST(62,w15.z,a2) ST(63,w15.w,a3)
#undef ST
        float acc = (a0 + a1) + (a2 + a3);
        float f = tanhf(acc + kpl);
        float v = f * wvl;
        #pragma unroll
        for (int off = 32; off > 0; off >>= 1) v += __shfl_xor(v, off);
        if (lane == 0) {
            int id = x_ids[b * SS + s];
            sScore[s] = (id == 0 || id == 1) ? -INFINITY : (v + bvv);
        }
    }
    __syncthreads();

    // block softmax over 200 scores (tid == s)
    float sc = (tid < SS) ? sScore[tid] : -INFINITY;
    float m = sc;
    #pragma unroll
    for (int off = 32; off > 0; off >>= 1) m = fmaxf(m, __shfl_xor(m, off));
    if (lane == 0) sRed[wave] = m;
    __syncthreads();
    const float M = fmaxf(fmaxf(sRed[0], sRed[1]), fmaxf(sRed[2], sRed[3]));
    float e = (tid < SS) ? expf(sc - M) : 0.f;
    float ssum = e;
    #pragma unroll
    for (int off = 32; off > 0; off >>= 1) ssum += __shfl_xor(ssum, off);
    if (lane == 0) sRed[4 + wave] = ssum;
    __syncthreads();
    const float Z = sRed[4] + sRed[5] + sRed[6] + sRed[7];

    const float wpg = sTh[6];
    int2* __restrict__ row = wslist + (size_t)b * 512;

    // repeat entries: slots [0, 200)
    if (tid < SS) {
        float val = (e > 0.f) ? (1.f - wpg) * (e / Z) : 0.f;
        row[tid] = make_int2(x_ids[b * SS + tid], __float_as_int(val));
    }
    // gap entries: slots [200, 399)
    if (tid < SS - 1) {
        float t  = tg[b * (SS - 1) + tid];
        int   c  = cla[b * (SS - 1) + tid];
        float c0 = (c == 0) ? t : 180.f;
        float c1 = (c == 1) ? t : 180.f;
        float c2 = (c == 2) ? t : 180.f;
        float g = sTh[0] * gauss_pdf(c0, sTh[7],  sTh[8])
                + sTh[1] * gauss_pdf(c1, sTh[9],  sTh[10])
                + sTh[2] * gauss_pdf(c1, sTh[11], sTh[12])
                + sTh[3] * gauss_pdf(c2, sTh[13], sTh[14])
                + sTh[4] * powf(c2, sTh[15]);
        row[SS + tid] = make_int2(x_ids[b * SS + tid + 1],
                                  __float_as_int(wpg * g));
    }
}

__global__ __launch_bounds__(256) void k2_scatter(
    const int2* __restrict__ wslist, float* __restrict__ out)
{
    const int b   = blockIdx.x;
    const int tid = threadIdx.x;
    const int2* __restrict__ row = wslist + (size_t)b * 512;
    float* __restrict__ orow = out + (size_t)b * VV;
    for (int e = tid; e < 2 * SS - 1; e += 256) {
        int2 p = row[e];
        float v = __int_as_float(p.y);
        if (v != 0.f) atomicAdd(orow + p.x, v);
    }
}

extern "C" void kernel_launch(void* const* d_in, const int* in_sizes, int n_in,
                              void* d_out, int out_size, void* d_ws, size_t ws_size,
                              hipStream_t stream) {
    const float* x     = (const float*)d_in[0];
    const int*   x_ids = (const int*)d_in[1];
    const float* tgp   = (const float*)d_in[2];
    const int*   cl    = (const int*)d_in[3];
    const float* Wq    = (const float*)d_in[4];
    const float* bq    = (const float*)d_in[5];
    const float* Wk    = (const float*)d_in[6];
    const float* bk    = (const float*)d_in[7];
    const float* wv    = (const float*)d_in[8];
    const float* bv    = (const float*)d_in[9];
    const float* th    = (const float*)d_in[10];
    float* out   = (float*)d_out;
    int2*  wlist = (int2*)d_ws;   // 512 rows * 512 entries * 8 B = 2 MB

    hipLaunchKernelGGL(k1_zero_and_compute, dim3(GRID), dim3(256), 0, stream,
                       x, x_ids, tgp, cl, Wq, bq, Wk, bk, wv, bv, th, out, wlist);
    hipLaunchKernelGGL(k2_scatter, dim3(BB), dim3(256), 0, stream,
                       wlist, out);
}